// Round 11
// baseline (226.078 us; speedup 1.0000x reference)
//
#include <hip/hip_runtime.h>
#include <math.h>

#define N_NODES 100000
#define N_EDGES 1000000
#define IN_F 128
#define H_F 64
#define THRV 0.1f
#define LN_EPS 1e-5f
#define GRID_AGG 4096

#define BSHIFT 9                 // 512 nodes per bucket
#define NB 196                   // ceil(100000 / 512)
#define BCAP 6144                // partition bucket capacity (mean 5120)
#define EPB 2048                 // edges per partition block
#define NPB ((N_EDGES + EPB - 1) / EPB)  // 489

static __device__ __forceinline__ float wave_sum(float x) {
  for (int o = 32; o > 0; o >>= 1) x += __shfl_xor(x, o, 64);
  return x;
}
static __device__ __forceinline__ float wave_max(float x) {
  for (int o = 32; o > 0; o >>= 1) x = fmaxf(x, __shfl_xor(x, o, 64));
  return x;
}
static __device__ __forceinline__ unsigned short f2bf(float f) {
  unsigned u = __float_as_uint(f);
  u = (u + 0x7FFFu + ((u >> 16) & 1u)) >> 16;  // RNE
  return (unsigned short)u;
}
static __device__ __forceinline__ float bf2f(unsigned short b) {
  return __uint_as_float(((unsigned)b) << 16);
}

// ---- CSR build: single-pass bucket partition (strided) -> packed CSR ----

// Partition edges into per-bucket fixed-stride regions as packed records:
// rec = src | (dstLocal << 17)   (src < 2^17, dstLocal < 2^9)
__global__ __launch_bounds__(256) void k_part(const int* __restrict__ src,
                                              const int* __restrict__ dst,
                                              int* __restrict__ bcnt,
                                              int* __restrict__ part) {
  __shared__ int h[NB];
  __shared__ int cur[NB];
  int t = threadIdx.x;
  for (int i = t; i < NB; i += 256) h[i] = 0;
  __syncthreads();
  int base = blockIdx.x * EPB;
  int d[8];
#pragma unroll
  for (int i = 0; i < 8; ++i) {
    int e = base + t + i * 256;
    d[i] = (e < N_EDGES) ? dst[e] : -1;
  }
#pragma unroll
  for (int i = 0; i < 8; ++i)
    if (d[i] >= 0) atomicAdd(&h[d[i] >> BSHIFT], 1);
  __syncthreads();
  for (int i = t; i < NB; i += 256) {
    int c = h[i];
    cur[i] = c ? atomicAdd(&bcnt[i], c) : 0;
  }
  __syncthreads();
#pragma unroll
  for (int i = 0; i < 8; ++i) {
    if (d[i] >= 0) {
      int e = base + t + i * 256;
      int b = d[i] >> BSHIFT;
      int pos = atomicAdd(&cur[b], 1);
      part[b * BCAP + pos] = src[e] | ((d[i] & 511) << 17);
    }
  }
}

// One block per bucket: scans bcnt itself for the packed base, then per-node
// degree count in LDS, scan, emit indeg/offs/dis1 (coalesced) and PACKED
// csr_src (scatter within the bucket's region).
__global__ __launch_bounds__(256) void k_build(
    const int* __restrict__ part, const int* __restrict__ bcnt,
    int* __restrict__ indeg, int* __restrict__ offs, float* __restrict__ dis1,
    int* __restrict__ csr_src) {
  __shared__ int cnt[512];
  __shared__ int slds[256];
  int b = blockIdx.x;
  int t = threadIdx.x;
  // packed base: sum of bcnt[0..b-1] (wave 0 computes, broadcast via LDS)
  __shared__ int obeg_s;
  if (t < 64) {
    int acc = 0;
    for (int i = t; i < NB; i += 64) acc += (i < b) ? bcnt[i] : 0;
    acc = (int)wave_sum((float)acc);  // small ints: exact in fp32
    if (t == 0) obeg_s = acc;
  }
  int pbeg = b * BCAP;
  int pend = pbeg + bcnt[b];
  for (int i = t; i < 512; i += 256) cnt[i] = 0;
  __syncthreads();
  int obeg = obeg_s;
  for (int i = pbeg + t; i < pend; i += 256)
    atomicAdd(&cnt[(part[i] >> 17) & 511], 1);
  __syncthreads();
  int a0 = cnt[2 * t], a1 = cnt[2 * t + 1];
  int pairsum = a0 + a1;
  slds[t] = pairsum;
  __syncthreads();
  int val = pairsum;
  for (int o = 1; o < 256; o <<= 1) {
    int y = (t >= o) ? slds[t - o] : 0;
    __syncthreads();
    val += y;
    slds[t] = val;
    __syncthreads();
  }
  int ex = val - pairsum;
  int off0 = ex, off1 = ex + a0;
  cnt[2 * t] = off0;  // reuse as scatter cursors (bucket-local)
  cnt[2 * t + 1] = off1;
  int node0 = (b << BSHIFT) + 2 * t;
  if (node0 < N_NODES) {
    indeg[node0] = a0;
    offs[node0] = obeg + off0;
    dis1[node0] = rsqrtf((float)a0 + 1.f);
  }
  if (node0 + 1 < N_NODES) {
    indeg[node0 + 1] = a1;
    offs[node0 + 1] = obeg + off1;
    dis1[node0 + 1] = rsqrtf((float)a1 + 1.f);
  }
  __syncthreads();
  for (int i = pbeg + t; i < pend; i += 256) {
    int p = part[i];
    int loc = (p >> 17) & 511;
    int pos = atomicAdd(&cnt[loc], 1);
    csr_src[obeg + pos] = p & 131071;
  }
}

// Wave-autonomous W-stationary GEMM: Y[r][64] = (X[r][K] @ W[K][64]) * scale_r.
// Only W staged in LDS (once, then read-only; no barriers in the K loop).
// SCALEMODE 0: scale_r = scale[r] (fp32 out). SCALEMODE 1: scale_r = dis2
// computed inline from (s=scale[], smm floats, indeg); bf16 out.
template <int K, int SCALEMODE>
__global__ __launch_bounds__(256) void k_gemm(const float* __restrict__ X,
                                              const float* __restrict__ W,
                                              const float* __restrict__ scale,
                                              const float* __restrict__ smm,
                                              const int* __restrict__ indeg,
                                              void* __restrict__ Yv, int nrows) {
  __shared__ __align__(16) float Ws[K][64];
  int t = threadIdx.x;
  for (int idx = t; idx < K * 16; idx += 256)
    ((float4*)&Ws[0][0])[idx] = ((const float4*)W)[idx];
  __syncthreads();

  int lane = t & 63;
  int wid = t >> 6;
  int tx = lane & 15, ty = lane >> 4;
  int rbase = blockIdx.x * 64 + wid * 16 + ty * 4;
  int r[4];
#pragma unroll
  for (int i = 0; i < 4; ++i) {
    int g = rbase + i;
    r[i] = (g < nrows) ? g : (nrows - 1);
  }
  int c0 = tx * 4;
  float acc[4][4] = {};

#pragma unroll 2
  for (int k = 0; k < K; k += 4) {
    float xv[4][4], wv[4][4];
#pragma unroll
    for (int i = 0; i < 4; ++i)
      *(float4*)xv[i] = *(const float4*)(X + (size_t)r[i] * K + k);
#pragma unroll
    for (int j = 0; j < 4; ++j)
      *(float4*)wv[j] = *(const float4*)&Ws[k + j][c0];
#pragma unroll
    for (int i = 0; i < 4; ++i)
#pragma unroll
      for (int kk = 0; kk < 4; ++kk)
#pragma unroll
        for (int j = 0; j < 4; ++j)
          acc[i][j] = fmaf(xv[i][kk], wv[kk][j], acc[i][j]);
  }

  float smin = 0.f, inv = 0.f;
  if constexpr (SCALEMODE == 1) {
    smin = smm[0];
    inv = 1.f / (smm[1] - smin + 1e-8f);
  }
#pragma unroll
  for (int i = 0; i < 4; ++i) {
    int gr = rbase + i;
    if (gr < nrows) {
      if constexpr (SCALEMODE == 1) {
        float sn = (scale[gr] - smin) * inv;  // scale[] = s[] here
        float dmask = (sn > THRV) ? (float)indeg[gr] : 0.f;
        float sc = rsqrtf(dmask + 1.f);
        ushort4 o;
        o.x = f2bf(acc[i][0] * sc);
        o.y = f2bf(acc[i][1] * sc);
        o.z = f2bf(acc[i][2] * sc);
        o.w = f2bf(acc[i][3] * sc);
        *(ushort4*)((unsigned short*)Yv + (size_t)gr * 64 + c0) = o;
      } else {
        float sc = scale[gr];
        float4 o;
        o.x = acc[i][0] * sc;
        o.y = acc[i][1] * sc;
        o.z = acc[i][2] * sc;
        o.w = acc[i][3] * sc;
        *(float4*)((float*)Yv + (size_t)gr * 64 + c0) = o;
      }
    }
  }
}

// Layer-0 aggregation over prescaled rows h1p (= h1 * dis1), fused with +b1,
// LayerNorm, ReLU, score s[v], block min/max partials. 16-deep gather unroll.
__global__ __launch_bounds__(256) void k_agg1(
    const float* __restrict__ h1p, const int* __restrict__ offs,
    const int* __restrict__ indeg, const int* __restrict__ csr_src,
    const float* __restrict__ dis1, const float* __restrict__ b1,
    const float* __restrict__ gamma, const float* __restrict__ beta,
    float* __restrict__ h, float* __restrict__ s, float* __restrict__ mmpart) {
  int lane = threadIdx.x & 63;
  int wid = blockIdx.x * 4 + (threadIdx.x >> 6);
  int nw = gridDim.x * 4;
  float bmin = __builtin_inff(), bmax = -__builtin_inff();
  for (int v = wid; v < N_NODES; v += nw) {
    int beg = offs[v];
    int deg = indeg[v];
    float disv = dis1[v];
    float acc = h1p[v * 64 + lane];  // self-loop term (prescaled)
    for (int c = 0; c < deg; c += 64) {
      int m = deg - c;
      if (m > 64) m = 64;
      int ul = (lane < m) ? csr_src[beg + c + lane] : 0;
      int j = 0;
      for (; j + 16 <= m; j += 16) {
        float a[16];
#pragma unroll
        for (int q = 0; q < 16; ++q) {
          int u = __shfl(ul, j + q);
          a[q] = h1p[u * 64 + lane];
        }
        float s0 = ((a[0] + a[1]) + (a[2] + a[3])) + ((a[4] + a[5]) + (a[6] + a[7]));
        float s1 = ((a[8] + a[9]) + (a[10] + a[11])) + ((a[12] + a[13]) + (a[14] + a[15]));
        acc += s0 + s1;
      }
      for (; j + 4 <= m; j += 4) {
        int u0 = __shfl(ul, j + 0), u1 = __shfl(ul, j + 1);
        int u2 = __shfl(ul, j + 2), u3 = __shfl(ul, j + 3);
        float a0 = h1p[u0 * 64 + lane], a1 = h1p[u1 * 64 + lane];
        float a2 = h1p[u2 * 64 + lane], a3 = h1p[u3 * 64 + lane];
        acc += (a0 + a1) + (a2 + a3);
      }
      for (; j < m; ++j) {
        int u = __shfl(ul, j);
        acc += h1p[u * 64 + lane];
      }
    }
    acc = disv * acc + b1[lane];
    float mu = wave_sum(acc) * (1.f / 64.f);
    float d = acc - mu;
    float var = wave_sum(d * d) * (1.f / 64.f);
    float hn = d * rsqrtf(var + LN_EPS) * gamma[lane] + beta[lane];
    hn = fmaxf(hn, 0.f);
    h[v * 64 + lane] = hn;
    float sv = sqrtf(wave_sum(hn * hn));  // wave-uniform
    if (lane == 0) s[v] = sv;
    bmin = fminf(bmin, sv);
    bmax = fmaxf(bmax, sv);
  }
  __shared__ float lmin[4], lmax[4];
  if ((threadIdx.x & 63) == 0) {
    lmin[threadIdx.x >> 6] = bmin;
    lmax[threadIdx.x >> 6] = bmax;
  }
  __syncthreads();
  if (threadIdx.x == 0) {
    mmpart[blockIdx.x * 2] = fminf(fminf(lmin[0], lmin[1]), fminf(lmin[2], lmin[3]));
    mmpart[blockIdx.x * 2 + 1] = fmaxf(fmaxf(lmax[0], lmax[1]), fmaxf(lmax[2], lmax[3]));
  }
}

__global__ void k_minmax2(const float* __restrict__ mmpart, float* __restrict__ smm,
                          int nblk) {
  int t = threadIdx.x;  // 256
  float mn = __builtin_inff(), mx = -__builtin_inff();
  for (int i = t; i < nblk; i += 256) {
    mn = fminf(mn, mmpart[i * 2]);
    mx = fmaxf(mx, mmpart[i * 2 + 1]);
  }
  for (int o = 32; o; o >>= 1) {
    mn = fminf(mn, __shfl_xor(mn, o, 64));
    mx = fmaxf(mx, __shfl_xor(mx, o, 64));
  }
  __shared__ float a[4], b[4];
  if ((t & 63) == 0) { a[t >> 6] = mn; b[t >> 6] = mx; }
  __syncthreads();
  if (t == 0) {
    smm[0] = fminf(fminf(a[0], a[1]), fminf(a[2], a[3]));
    smm[1] = fmaxf(fmaxf(b[0], b[1]), fmaxf(b[2], b[3]));
  }
}

// Layer-1 masked aggregation over bf16 prescaled rows h2b (= (h@W2)*dis2),
// fused with +b2 and log_softmax into d_out. 16-deep gather unroll.
__global__ __launch_bounds__(256) void k_agg2(
    const unsigned short* __restrict__ h2b, const int* __restrict__ offs,
    const int* __restrict__ indeg, const int* __restrict__ csr_src,
    const float* __restrict__ s, const float* __restrict__ smm,
    const float* __restrict__ b2, float* __restrict__ out) {
  int lane = threadIdx.x & 63;
  int wid = blockIdx.x * 4 + (threadIdx.x >> 6);
  int nw = gridDim.x * 4;
  float smin = smm[0];
  float inv = 1.f / (smm[1] - smin + 1e-8f);
  for (int v = wid; v < N_NODES; v += nw) {
    int deg = indeg[v];
    float sn = (s[v] - smin) * inv;
    bool on = sn > THRV;
    float acc = bf2f(h2b[v * 64 + lane]);  // self term (prescaled by dis2[v])
    if (on) {
      int beg = offs[v];
      for (int c = 0; c < deg; c += 64) {
        int m = deg - c;
        if (m > 64) m = 64;
        int ul = (lane < m) ? csr_src[beg + c + lane] : 0;
        int j = 0;
        for (; j + 16 <= m; j += 16) {
          float a[16];
#pragma unroll
          for (int q = 0; q < 16; ++q) {
            int u = __shfl(ul, j + q);
            a[q] = bf2f(h2b[u * 64 + lane]);
          }
          float s0 = ((a[0] + a[1]) + (a[2] + a[3])) + ((a[4] + a[5]) + (a[6] + a[7]));
          float s1 = ((a[8] + a[9]) + (a[10] + a[11])) + ((a[12] + a[13]) + (a[14] + a[15]));
          acc += s0 + s1;
        }
        for (; j + 4 <= m; j += 4) {
          int u0 = __shfl(ul, j + 0), u1 = __shfl(ul, j + 1);
          int u2 = __shfl(ul, j + 2), u3 = __shfl(ul, j + 3);
          float a0 = bf2f(h2b[u0 * 64 + lane]), a1 = bf2f(h2b[u1 * 64 + lane]);
          float a2 = bf2f(h2b[u2 * 64 + lane]), a3 = bf2f(h2b[u3 * 64 + lane]);
          acc += (a0 + a1) + (a2 + a3);
        }
        for (; j < m; ++j) {
          int u = __shfl(ul, j);
          acc += bf2f(h2b[u * 64 + lane]);
        }
      }
    }
    float disv = rsqrtf((on ? (float)deg : 0.f) + 1.f);
    acc = disv * acc + b2[lane];
    float m = wave_max(acc);
    float p = expf(acc - m);
    float sum = wave_sum(p);
    out[v * 64 + lane] = acc - m - logf(sum);
  }
}

extern "C" void kernel_launch(void* const* d_in, const int* in_sizes, int n_in,
                              void* d_out, int out_size, void* d_ws, size_t ws_size,
                              hipStream_t stream) {
  const float* x = (const float*)d_in[0];
  const float* W1 = (const float*)d_in[1];
  const float* b1 = (const float*)d_in[2];
  const float* W2 = (const float*)d_in[3];
  const float* b2 = (const float*)d_in[4];
  const float* gamma = (const float*)d_in[5];
  const float* beta = (const float*)d_in[6];
  const int* ei = (const int*)d_in[7];
  const int* src = ei;
  const int* dst = ei + N_EDGES;
  float* out = (float*)d_out;

  char* ws = (char*)d_ws;
  size_t off = 0;
  auto alloc = [&](size_t bytes) {
    void* p = ws + off;
    off += (bytes + 255) & ~(size_t)255;
    return p;
  };
  int* indeg = (int*)alloc(N_NODES * 4);
  int* offs = (int*)alloc(N_NODES * 4);
  int* bcnt = (int*)alloc(NB * 4);
  float* mmpart = (float*)alloc(GRID_AGG * 2 * 4);
  float* smm = (float*)alloc(256);
  int* csr_src = (int*)alloc((size_t)N_EDGES * 4);  // packed
  float* s = (float*)alloc(N_NODES * 4);
  float* dis1 = (float*)alloc(N_NODES * 4);
  float* h1 = (float*)alloc((size_t)N_NODES * 64 * 4);
  float* h = (float*)alloc((size_t)N_NODES * 64 * 4);
  int* part = (int*)h1;  // alias: strided partition buffer, dead before gemm1
  unsigned short* h2b = (unsigned short*)h1;  // alias: h1 dead after agg1
  (void)ws_size;
  (void)n_in;
  (void)in_sizes;
  (void)out_size;

  hipMemsetAsync(bcnt, 0, NB * 4, stream);
  k_part<<<NPB, 256, 0, stream>>>(src, dst, bcnt, part);
  k_build<<<NB, 256, 0, stream>>>(part, bcnt, indeg, offs, dis1, csr_src);
  int gemm_grid = (N_NODES + 63) / 64;  // 1563
  k_gemm<IN_F, 0><<<gemm_grid, 256, 0, stream>>>(x, W1, dis1, nullptr, nullptr,
                                                 h1, N_NODES);
  k_agg1<<<GRID_AGG, 256, 0, stream>>>(h1, offs, indeg, csr_src, dis1, b1, gamma,
                                       beta, h, s, mmpart);
  k_minmax2<<<1, 256, 0, stream>>>(mmpart, smm, GRID_AGG);
  k_gemm<H_F, 1><<<gemm_grid, 256, 0, stream>>>(h, W2, s, smm, indeg, h2b,
                                                N_NODES);
  k_agg2<<<GRID_AGG, 256, 0, stream>>>(h2b, offs, indeg, csr_src, s, smm, b2,
                                       out);
}

// Round 12
// 204.966 us; speedup vs baseline: 1.1030x; 1.1030x over previous
//
#include <hip/hip_runtime.h>
#include <math.h>

#define N_NODES 100000
#define N_EDGES 1000000
#define IN_F 128
#define H_F 64
#define THRV 0.1f
#define LN_EPS 1e-5f
#define GRID_AGG 2048

#define BSHIFT 9                 // 512 nodes per bucket
#define NB 196                   // ceil(100000 / 512)
#define BCAP 6144                // partition bucket capacity (mean 5120)
#define EPB 2048                 // edges per partition block
#define NPB ((N_EDGES + EPB - 1) / EPB)  // 489

static __device__ __forceinline__ float wave_sum(float x) {
  for (int o = 32; o > 0; o >>= 1) x += __shfl_xor(x, o, 64);
  return x;
}
static __device__ __forceinline__ float wave_max(float x) {
  for (int o = 32; o > 0; o >>= 1) x = fmaxf(x, __shfl_xor(x, o, 64));
  return x;
}
static __device__ __forceinline__ unsigned short f2bf(float f) {
  unsigned u = __float_as_uint(f);
  u = (u + 0x7FFFu + ((u >> 16) & 1u)) >> 16;  // RNE
  return (unsigned short)u;
}
static __device__ __forceinline__ float bf2f(unsigned short b) {
  return __uint_as_float(((unsigned)b) << 16);
}

// ---- CSR build: single-pass bucket partition (strided) -> packed CSR ----

// Partition edges into per-bucket fixed-stride regions as packed records:
// rec = src | (dstLocal << 17)   (src < 2^17, dstLocal < 2^9)
__global__ __launch_bounds__(256) void k_part(const int* __restrict__ src,
                                              const int* __restrict__ dst,
                                              int* __restrict__ bcnt,
                                              int* __restrict__ part) {
  __shared__ int h[NB];
  __shared__ int cur[NB];
  int t = threadIdx.x;
  for (int i = t; i < NB; i += 256) h[i] = 0;
  __syncthreads();
  int base = blockIdx.x * EPB;
  int d[8];
#pragma unroll
  for (int i = 0; i < 8; ++i) {
    int e = base + t + i * 256;
    d[i] = (e < N_EDGES) ? dst[e] : -1;
  }
#pragma unroll
  for (int i = 0; i < 8; ++i)
    if (d[i] >= 0) atomicAdd(&h[d[i] >> BSHIFT], 1);
  __syncthreads();
  for (int i = t; i < NB; i += 256) {
    int c = h[i];
    cur[i] = c ? atomicAdd(&bcnt[i], c) : 0;
  }
  __syncthreads();
#pragma unroll
  for (int i = 0; i < 8; ++i) {
    if (d[i] >= 0) {
      int e = base + t + i * 256;
      int b = d[i] >> BSHIFT;
      int pos = atomicAdd(&cur[b], 1);
      part[b * BCAP + pos] = src[e] | ((d[i] & 511) << 17);
    }
  }
}

// One block per bucket: scans bcnt itself for the packed base, then per-node
// degree count in LDS, scan, emit indeg/offs/dis1 (coalesced) and PACKED
// csr_src (scatter within the bucket's region).
__global__ __launch_bounds__(256) void k_build(
    const int* __restrict__ part, const int* __restrict__ bcnt,
    int* __restrict__ indeg, int* __restrict__ offs, float* __restrict__ dis1,
    int* __restrict__ csr_src) {
  __shared__ int cnt[512];
  __shared__ int slds[256];
  int b = blockIdx.x;
  int t = threadIdx.x;
  // packed base: sum of bcnt[0..b-1] (wave 0 computes, broadcast via LDS)
  __shared__ int obeg_s;
  if (t < 64) {
    int acc = 0;
    for (int i = t; i < NB; i += 64) acc += (i < b) ? bcnt[i] : 0;
    acc = (int)wave_sum((float)acc);  // small ints: exact in fp32
    if (t == 0) obeg_s = acc;
  }
  int pbeg = b * BCAP;
  int pend = pbeg + bcnt[b];
  for (int i = t; i < 512; i += 256) cnt[i] = 0;
  __syncthreads();
  int obeg = obeg_s;
  for (int i = pbeg + t; i < pend; i += 256)
    atomicAdd(&cnt[(part[i] >> 17) & 511], 1);
  __syncthreads();
  int a0 = cnt[2 * t], a1 = cnt[2 * t + 1];
  int pairsum = a0 + a1;
  slds[t] = pairsum;
  __syncthreads();
  int val = pairsum;
  for (int o = 1; o < 256; o <<= 1) {
    int y = (t >= o) ? slds[t - o] : 0;
    __syncthreads();
    val += y;
    slds[t] = val;
    __syncthreads();
  }
  int ex = val - pairsum;
  int off0 = ex, off1 = ex + a0;
  cnt[2 * t] = off0;  // reuse as scatter cursors (bucket-local)
  cnt[2 * t + 1] = off1;
  int node0 = (b << BSHIFT) + 2 * t;
  if (node0 < N_NODES) {
    indeg[node0] = a0;
    offs[node0] = obeg + off0;
    dis1[node0] = rsqrtf((float)a0 + 1.f);
  }
  if (node0 + 1 < N_NODES) {
    indeg[node0 + 1] = a1;
    offs[node0 + 1] = obeg + off1;
    dis1[node0 + 1] = rsqrtf((float)a1 + 1.f);
  }
  __syncthreads();
  for (int i = pbeg + t; i < pend; i += 256) {
    int p = part[i];
    int loc = (p >> 17) & 511;
    int pos = atomicAdd(&cnt[loc], 1);
    csr_src[obeg + pos] = p & 131071;
  }
}

// Wave-autonomous W-stationary GEMM: Y[r][64] = (X[r][K] @ W[K][64]) * scale_r.
// Only W staged in LDS (once, then read-only; no barriers in the K loop).
// SCALEMODE 0: scale_r = scale[r] (fp32 out). SCALEMODE 1: scale_r = dis2
// computed inline from (s=scale[], smm floats, indeg); bf16 out.
template <int K, int SCALEMODE>
__global__ __launch_bounds__(256) void k_gemm(const float* __restrict__ X,
                                              const float* __restrict__ W,
                                              const float* __restrict__ scale,
                                              const float* __restrict__ smm,
                                              const int* __restrict__ indeg,
                                              void* __restrict__ Yv, int nrows) {
  __shared__ __align__(16) float Ws[K][64];
  int t = threadIdx.x;
  for (int idx = t; idx < K * 16; idx += 256)
    ((float4*)&Ws[0][0])[idx] = ((const float4*)W)[idx];
  __syncthreads();

  int lane = t & 63;
  int wid = t >> 6;
  int tx = lane & 15, ty = lane >> 4;
  int rbase = blockIdx.x * 64 + wid * 16 + ty * 4;
  int r[4];
#pragma unroll
  for (int i = 0; i < 4; ++i) {
    int g = rbase + i;
    r[i] = (g < nrows) ? g : (nrows - 1);
  }
  int c0 = tx * 4;
  float acc[4][4] = {};

#pragma unroll 2
  for (int k = 0; k < K; k += 4) {
    float xv[4][4], wv[4][4];
#pragma unroll
    for (int i = 0; i < 4; ++i)
      *(float4*)xv[i] = *(const float4*)(X + (size_t)r[i] * K + k);
#pragma unroll
    for (int j = 0; j < 4; ++j)
      *(float4*)wv[j] = *(const float4*)&Ws[k + j][c0];
#pragma unroll
    for (int i = 0; i < 4; ++i)
#pragma unroll
      for (int kk = 0; kk < 4; ++kk)
#pragma unroll
        for (int j = 0; j < 4; ++j)
          acc[i][j] = fmaf(xv[i][kk], wv[kk][j], acc[i][j]);
  }

  float smin = 0.f, inv = 0.f;
  if constexpr (SCALEMODE == 1) {
    smin = smm[0];
    inv = 1.f / (smm[1] - smin + 1e-8f);
  }
#pragma unroll
  for (int i = 0; i < 4; ++i) {
    int gr = rbase + i;
    if (gr < nrows) {
      if constexpr (SCALEMODE == 1) {
        float sn = (scale[gr] - smin) * inv;  // scale[] = s[] here
        float dmask = (sn > THRV) ? (float)indeg[gr] : 0.f;
        float sc = rsqrtf(dmask + 1.f);
        ushort4 o;
        o.x = f2bf(acc[i][0] * sc);
        o.y = f2bf(acc[i][1] * sc);
        o.z = f2bf(acc[i][2] * sc);
        o.w = f2bf(acc[i][3] * sc);
        *(ushort4*)((unsigned short*)Yv + (size_t)gr * 64 + c0) = o;
      } else {
        float sc = scale[gr];
        float4 o;
        o.x = acc[i][0] * sc;
        o.y = acc[i][1] * sc;
        o.z = acc[i][2] * sc;
        o.w = acc[i][3] * sc;
        *(float4*)((float*)Yv + (size_t)gr * 64 + c0) = o;
      }
    }
  }
}

// Layer-0 aggregation over prescaled rows h1p (= h1 * dis1), fused with +b1,
// LayerNorm, ReLU, score s[v], block min/max partials. (Round-6 body, verbatim.)
__global__ __launch_bounds__(256) void k_agg1(
    const float* __restrict__ h1p, const int* __restrict__ offs,
    const int* __restrict__ indeg, const int* __restrict__ csr_src,
    const float* __restrict__ dis1, const float* __restrict__ b1,
    const float* __restrict__ gamma, const float* __restrict__ beta,
    float* __restrict__ h, float* __restrict__ s, float* __restrict__ mmpart) {
  int lane = threadIdx.x & 63;
  int wid = blockIdx.x * 4 + (threadIdx.x >> 6);
  int nw = gridDim.x * 4;
  float bmin = __builtin_inff(), bmax = -__builtin_inff();
  for (int v = wid; v < N_NODES; v += nw) {
    int beg = offs[v];
    int deg = indeg[v];
    float disv = dis1[v];
    float acc = h1p[v * 64 + lane];  // self-loop term (prescaled)
    for (int c = 0; c < deg; c += 64) {
      int m = deg - c;
      if (m > 64) m = 64;
      int ul = (lane < m) ? csr_src[beg + c + lane] : 0;
      int j = 0;
      for (; j + 8 <= m; j += 8) {
        int u0 = __shfl(ul, j + 0), u1 = __shfl(ul, j + 1);
        int u2 = __shfl(ul, j + 2), u3 = __shfl(ul, j + 3);
        int u4 = __shfl(ul, j + 4), u5 = __shfl(ul, j + 5);
        int u6 = __shfl(ul, j + 6), u7 = __shfl(ul, j + 7);
        float a0 = h1p[u0 * 64 + lane], a1 = h1p[u1 * 64 + lane];
        float a2 = h1p[u2 * 64 + lane], a3 = h1p[u3 * 64 + lane];
        float a4 = h1p[u4 * 64 + lane], a5 = h1p[u5 * 64 + lane];
        float a6 = h1p[u6 * 64 + lane], a7 = h1p[u7 * 64 + lane];
        acc += ((a0 + a1) + (a2 + a3)) + ((a4 + a5) + (a6 + a7));
      }
      for (; j < m; ++j) {
        int u = __shfl(ul, j);
        acc += h1p[u * 64 + lane];
      }
    }
    acc = disv * acc + b1[lane];
    float mu = wave_sum(acc) * (1.f / 64.f);
    float d = acc - mu;
    float var = wave_sum(d * d) * (1.f / 64.f);
    float hn = d * rsqrtf(var + LN_EPS) * gamma[lane] + beta[lane];
    hn = fmaxf(hn, 0.f);
    h[v * 64 + lane] = hn;
    float sv = sqrtf(wave_sum(hn * hn));  // wave-uniform
    if (lane == 0) s[v] = sv;
    bmin = fminf(bmin, sv);
    bmax = fmaxf(bmax, sv);
  }
  __shared__ float lmin[4], lmax[4];
  if ((threadIdx.x & 63) == 0) {
    lmin[threadIdx.x >> 6] = bmin;
    lmax[threadIdx.x >> 6] = bmax;
  }
  __syncthreads();
  if (threadIdx.x == 0) {
    mmpart[blockIdx.x * 2] = fminf(fminf(lmin[0], lmin[1]), fminf(lmin[2], lmin[3]));
    mmpart[blockIdx.x * 2 + 1] = fmaxf(fmaxf(lmax[0], lmax[1]), fmaxf(lmax[2], lmax[3]));
  }
}

__global__ void k_minmax2(const float* __restrict__ mmpart, float* __restrict__ smm,
                          int nblk) {
  int t = threadIdx.x;  // 256
  float mn = __builtin_inff(), mx = -__builtin_inff();
  for (int i = t; i < nblk; i += 256) {
    mn = fminf(mn, mmpart[i * 2]);
    mx = fmaxf(mx, mmpart[i * 2 + 1]);
  }
  for (int o = 32; o; o >>= 1) {
    mn = fminf(mn, __shfl_xor(mn, o, 64));
    mx = fmaxf(mx, __shfl_xor(mx, o, 64));
  }
  __shared__ float a[4], b[4];
  if ((t & 63) == 0) { a[t >> 6] = mn; b[t >> 6] = mx; }
  __syncthreads();
  if (t == 0) {
    smm[0] = fminf(fminf(a[0], a[1]), fminf(a[2], a[3]));
    smm[1] = fmaxf(fmaxf(b[0], b[1]), fmaxf(b[2], b[3]));
  }
}

// Layer-1 masked aggregation over bf16 prescaled rows h2b (= (h@W2)*dis2),
// fused with +b2 and log_softmax into d_out. disv recomputed inline.
__global__ __launch_bounds__(256) void k_agg2(
    const unsigned short* __restrict__ h2b, const int* __restrict__ offs,
    const int* __restrict__ indeg, const int* __restrict__ csr_src,
    const float* __restrict__ s, const float* __restrict__ smm,
    const float* __restrict__ b2, float* __restrict__ out) {
  int lane = threadIdx.x & 63;
  int wid = blockIdx.x * 4 + (threadIdx.x >> 6);
  int nw = gridDim.x * 4;
  float smin = smm[0];
  float inv = 1.f / (smm[1] - smin + 1e-8f);
  for (int v = wid; v < N_NODES; v += nw) {
    int deg = indeg[v];
    float sn = (s[v] - smin) * inv;
    bool on = sn > THRV;
    float acc = bf2f(h2b[v * 64 + lane]);  // self term (prescaled by dis2[v])
    if (on) {
      int beg = offs[v];
      for (int c = 0; c < deg; c += 64) {
        int m = deg - c;
        if (m > 64) m = 64;
        int ul = (lane < m) ? csr_src[beg + c + lane] : 0;
        int j = 0;
        for (; j + 8 <= m; j += 8) {
          int u0 = __shfl(ul, j + 0), u1 = __shfl(ul, j + 1);
          int u2 = __shfl(ul, j + 2), u3 = __shfl(ul, j + 3);
          int u4 = __shfl(ul, j + 4), u5 = __shfl(ul, j + 5);
          int u6 = __shfl(ul, j + 6), u7 = __shfl(ul, j + 7);
          float a0 = bf2f(h2b[u0 * 64 + lane]), a1 = bf2f(h2b[u1 * 64 + lane]);
          float a2 = bf2f(h2b[u2 * 64 + lane]), a3 = bf2f(h2b[u3 * 64 + lane]);
          float a4 = bf2f(h2b[u4 * 64 + lane]), a5 = bf2f(h2b[u5 * 64 + lane]);
          float a6 = bf2f(h2b[u6 * 64 + lane]), a7 = bf2f(h2b[u7 * 64 + lane]);
          acc += ((a0 + a1) + (a2 + a3)) + ((a4 + a5) + (a6 + a7));
        }
        for (; j < m; ++j) {
          int u = __shfl(ul, j);
          acc += bf2f(h2b[u * 64 + lane]);
        }
      }
    }
    float disv = rsqrtf((on ? (float)deg : 0.f) + 1.f);
    acc = disv * acc + b2[lane];
    float m = wave_max(acc);
    float p = expf(acc - m);
    float sum = wave_sum(p);
    out[v * 64 + lane] = acc - m - logf(sum);
  }
}

extern "C" void kernel_launch(void* const* d_in, const int* in_sizes, int n_in,
                              void* d_out, int out_size, void* d_ws, size_t ws_size,
                              hipStream_t stream) {
  const float* x = (const float*)d_in[0];
  const float* W1 = (const float*)d_in[1];
  const float* b1 = (const float*)d_in[2];
  const float* W2 = (const float*)d_in[3];
  const float* b2 = (const float*)d_in[4];
  const float* gamma = (const float*)d_in[5];
  const float* beta = (const float*)d_in[6];
  const int* ei = (const int*)d_in[7];
  const int* src = ei;
  const int* dst = ei + N_EDGES;
  float* out = (float*)d_out;

  char* ws = (char*)d_ws;
  size_t off = 0;
  auto alloc = [&](size_t bytes) {
    void* p = ws + off;
    off += (bytes + 255) & ~(size_t)255;
    return p;
  };
  int* indeg = (int*)alloc(N_NODES * 4);
  int* offs = (int*)alloc(N_NODES * 4);
  int* bcnt = (int*)alloc(NB * 4);
  float* mmpart = (float*)alloc(GRID_AGG * 2 * 4);
  float* smm = (float*)alloc(256);
  int* csr_src = (int*)alloc((size_t)N_EDGES * 4);  // packed
  float* s = (float*)alloc(N_NODES * 4);
  float* dis1 = (float*)alloc(N_NODES * 4);
  float* h1 = (float*)alloc((size_t)N_NODES * 64 * 4);
  float* h = (float*)alloc((size_t)N_NODES * 64 * 4);
  int* part = (int*)h1;  // alias: strided partition buffer, dead before gemm1
  unsigned short* h2b = (unsigned short*)h1;  // alias: h1 dead after agg1
  (void)ws_size;
  (void)n_in;
  (void)in_sizes;
  (void)out_size;

  hipMemsetAsync(bcnt, 0, NB * 4, stream);
  k_part<<<NPB, 256, 0, stream>>>(src, dst, bcnt, part);
  k_build<<<NB, 256, 0, stream>>>(part, bcnt, indeg, offs, dis1, csr_src);
  int gemm_grid = (N_NODES + 63) / 64;  // 1563
  k_gemm<IN_F, 0><<<gemm_grid, 256, 0, stream>>>(x, W1, dis1, nullptr, nullptr,
                                                 h1, N_NODES);
  k_agg1<<<GRID_AGG, 256, 0, stream>>>(h1, offs, indeg, csr_src, dis1, b1, gamma,
                                       beta, h, s, mmpart);
  k_minmax2<<<1, 256, 0, stream>>>(mmpart, smm, GRID_AGG);
  k_gemm<H_F, 1><<<gemm_grid, 256, 0, stream>>>(h, W2, s, smm, indeg, h2b,
                                                N_NODES);
  k_agg2<<<GRID_AGG, 256, 0, stream>>>(h2b, offs, indeg, csr_src, s, smm, b2,
                                       out);
}